// Round 1
// baseline (147.213 us; speedup 1.0000x reference)
//
#include <hip/hip_runtime.h>
#include <stdint.h>

#define B   256
#define IU  8      // in_units (i)
#define JC  1152   // in_channels (j)
#define NN  10     // num_units (n)
#define UU  16     // unit_size (u)
#define NU  160    // NN*UU
#define JN  11520  // JC*NN
#define WROW 1280  // NN*UU*IU, floats per j in W
#define NP  9216   // IU*JC, x row length
#define KB  72     // k-split count (16 j per slice, 2 chunks of 8)

typedef short bf16x8 __attribute__((ext_vector_type(8)));
typedef float f32x4  __attribute__((ext_vector_type(4)));

__device__ __forceinline__ short f2bf(float f) {
    union { float f; uint32_t u; } cv; cv.f = f;
    uint32_t u = cv.u;
    uint32_t r = u + 0x7fffu + ((u >> 16) & 1u);
    return (short)(r >> 16);
}
__device__ __forceinline__ float bf2f(short h) {
    union { uint32_t u; float f; } cv; cv.u = ((uint32_t)(unsigned short)h) << 16;
    return cv.f;
}
__device__ __forceinline__ uint32_t bfbits(float f) {
    union { float f; uint32_t u; } cv; cv.f = f;
    return (cv.u + 0x7fffu + ((cv.u >> 16) & 1u)) >> 16;
}
__device__ __forceinline__ uint32_t pk2(float a, float b) {
    return bfbits(a) | (bfbits(b) << 16);
}

// ---------------- pass 1 MFMA GEMM: s = x[256,9216] * (c*W)^T ------------
// grid (KB=72 k-splits of 16 j, 8 m-tiles of 32 b) = 576 blocks; 4 waves.
// c-normalization fused: cc = eblog[j,n] * (1/expsum[n]); eblog==nullptr on
// iter 0 -> cc = 1/JC exactly (softmax of zeros).
__global__ void __launch_bounds__(256, 2)
k_gemm1(const float* __restrict__ xg, const float* __restrict__ wg,
        const float* __restrict__ eblog, const float* __restrict__ expsum,
        float* __restrict__ s_part) {
    const int kb = blockIdx.x, mt = blockIdx.y;
    const int tid = threadIdx.x;
    const int wv = tid >> 6, lane = tid & 63;
    const int q = lane >> 4, l16 = lane & 15;
    const int b0 = mt * 32;
    const int jb0 = kb * 16;
    const int mfrag = wv >> 1;          // 0..1
    const int ntb = (wv & 1) * 5;       // 0 or 5

    __shared__ __align__(16) short As[8 * 32 * 8];   // 4 KB  [jj][bl][ii]
    __shared__ __align__(16) short Bs[8 * 160 * 8];  // 20 KB [jj][nu][ii]
    __shared__ float inv_s[NN];

    if (eblog && tid < NN) inv_s[tid] = 1.f / expsum[tid];

    f32x4 acc[5];
    #pragma unroll
    for (int nt = 0; nt < 5; ++nt) acc[nt] = (f32x4){0.f, 0.f, 0.f, 0.f};

    for (int jc = 0; jc < 2; ++jc) {
        const int j0 = jb0 + jc * 8;
        __syncthreads();                // also publishes inv_s on first pass
        // stage As: x[b0+bl][ii][j0+jj] -> As[jj][bl][ii]  (512 float4s)
        #pragma unroll
        for (int p = 0; p < 2; ++p) {
            int idx = tid + 256 * p;        // 0..511
            int jq  = idx & 1;
            int row = idx >> 1;             // bl*8+ii
            int bl = row >> 3, ii = row & 7;
            const float4 xv = *reinterpret_cast<const float4*>(
                &xg[(size_t)(b0 + bl) * NP + ii * JC + j0 + jq*4]);
            int jjb = jq * 4;
            As[((jjb+0)*32 + bl)*8 + ii] = f2bf(xv.x);
            As[((jjb+1)*32 + bl)*8 + ii] = f2bf(xv.y);
            As[((jjb+2)*32 + bl)*8 + ii] = f2bf(xv.z);
            As[((jjb+3)*32 + bl)*8 + ii] = f2bf(xv.w);
        }
        // stage Bs: one W row (8 i, 32B contig) -> one ds_write_b128
        #pragma unroll
        for (int p = 0; p < 5; ++p) {
            int ridx = tid + 256 * p;       // 0..1279 = jj*160+nu
            int jj = ridx / 160;
            int nu = ridx - jj * 160;
            int j  = j0 + jj;
            const float4* wp = reinterpret_cast<const float4*>(
                &wg[(size_t)j * WROW + (size_t)nu * 8]);
            float4 f0 = wp[0], f1 = wp[1];
            int nn = nu >> 4;
            float cc = eblog ? eblog[j * NN + nn] * inv_s[nn]
                             : (1.0f / (float)JC);
            uint4 d;
            d.x = pk2(f0.x * cc, f0.y * cc);
            d.y = pk2(f0.z * cc, f0.w * cc);
            d.z = pk2(f1.x * cc, f1.y * cc);
            d.w = pk2(f1.z * cc, f1.w * cc);
            *reinterpret_cast<uint4*>(&Bs[(size_t)ridx * 8]) = d;
        }
        __syncthreads();
        #pragma unroll
        for (int s = 0; s < 2; ++s) {
            int jj = s*4 + q;
            bf16x8 av = *reinterpret_cast<const bf16x8*>(
                &As[((jj*32 + mfrag*16 + l16) << 3)]);
            #pragma unroll
            for (int nt = 0; nt < 5; ++nt) {
                bf16x8 bv = *reinterpret_cast<const bf16x8*>(
                    &Bs[((jj*160 + (ntb + nt)*16 + l16) << 3)]);
                acc[nt] = __builtin_amdgcn_mfma_f32_16x16x32_bf16(av, bv, acc[nt], 0, 0, 0);
            }
        }
    }
    // commit: b_local = mfrag*16 + q*4 + reg, nu = (ntb+nt)*16 + l16
    float* dst = s_part + (size_t)(kb*8 + mt) * 5120;
    #pragma unroll
    for (int nt = 0; nt < 5; ++nt)
        #pragma unroll
        for (int reg = 0; reg < 4; ++reg)
            dst[(mfrag*16 + q*4 + reg) * 160 + (ntb + nt)*16 + l16] = acc[nt][reg];
}

// ---------------- fused reduce (72 slices) + squash ----------------------
__global__ void __launch_bounds__(320, 2)
k_reduce_s(const float* __restrict__ s_part, float* __restrict__ vdst) {
    const int b = blockIdx.x, tid = threadIdx.x;
    const int t = tid % 160, kq = tid / 160;
    const int mt = b >> 5, bl = b & 31;
    const size_t off = (size_t)mt * 5120 + bl * 160 + t;

    float s = 0.f;
    for (int r = 0; r < 36; ++r)
        s += s_part[(size_t)(kq*36 + r) * 40960 + off];

    __shared__ float red[2][160];
    __shared__ float sv[NU];
    __shared__ float fb[UU];
    red[kq][t] = s;
    __syncthreads();
    if (tid < NU) sv[tid] = red[0][tid] + red[1][tid];
    __syncthreads();
    if (tid < UU) {
        float m = 0.f;
        #pragma unroll
        for (int n = 0; n < NN; ++n) { float z = sv[n*16 + tid]; m = fmaf(z, z, m); }
        fb[tid] = sqrtf(m) / (1.f + m);
    }
    __syncthreads();
    if (tid < NU)
        vdst[(size_t)b * NU + tid] = sv[tid] * fb[tid & 15];
}

// ---------------- pass 2a: G[nu][n'] = sum_b v[b][nu] * x[b][n'] ---------
// Block (0,0) also zeroes expsum for the following k_wg_db (stream-ordered).
__global__ void __launch_bounds__(256, 2)
k_vxg(const float* __restrict__ vg, const float* __restrict__ xg,
      float* __restrict__ G, float* __restrict__ expsum) {
    const int np0 = blockIdx.x * 64, m0 = blockIdx.y * 32;
    const int tid = threadIdx.x;
    const int wv = tid >> 6, lane = tid & 63;
    const int q = lane >> 4, l16 = lane & 15;

    if (blockIdx.x == 0 && blockIdx.y == 0 && tid < NN) expsum[tid] = 0.f;

    __shared__ __align__(16) short Ash[8 * 32 * 8];
    __shared__ __align__(16) short Asl[8 * 32 * 8];
    __shared__ __align__(16) short Bsh[8 * 64 * 8];
    __shared__ __align__(16) short Bsl[8 * 64 * 8];

    f32x4 acc[2];
    acc[0] = (f32x4){0.f,0.f,0.f,0.f};
    acc[1] = (f32x4){0.f,0.f,0.f,0.f};

    for (int ks = 0; ks < 4; ++ks) {
        const int b0 = ks * 64;
        __syncthreads();
        #pragma unroll
        for (int p = 0; p < 8; ++p) {
            int idx = tid + 256 * p;
            int bb = idx >> 5, ml = idx & 31;
            float vv = vg[(size_t)(b0 + bb) * NU + m0 + ml];
            short hi = f2bf(vv);
            short lo = f2bf(vv - bf2f(hi));
            int a = ((bb >> 3) * 32 + ml) * 8 + (bb & 7);
            Ash[a] = hi; Asl[a] = lo;
        }
        #pragma unroll
        for (int p = 0; p < 16; ++p) {
            int idx = tid + 256 * p;
            int bb = idx >> 6, nl = idx & 63;
            float xv = xg[(size_t)(b0 + bb) * NP + np0 + nl];
            short hi = f2bf(xv);
            short lo = f2bf(xv - bf2f(hi));
            int a = ((bb >> 3) * 64 + nl) * 8 + (bb & 7);
            Bsh[a] = hi; Bsl[a] = lo;
        }
        __syncthreads();
        #pragma unroll
        for (int s = 0; s < 2; ++s) {
            int kc = s*4 + q;
            bf16x8 bh = *reinterpret_cast<const bf16x8*>(&Bsh[((kc*64 + wv*16 + l16) << 3)]);
            bf16x8 bl = *reinterpret_cast<const bf16x8*>(&Bsl[((kc*64 + wv*16 + l16) << 3)]);
            #pragma unroll
            for (int mtl = 0; mtl < 2; ++mtl) {
                bf16x8 ah = *reinterpret_cast<const bf16x8*>(&Ash[((kc*32 + mtl*16 + l16) << 3)]);
                bf16x8 al = *reinterpret_cast<const bf16x8*>(&Asl[((kc*32 + mtl*16 + l16) << 3)]);
                acc[mtl] = __builtin_amdgcn_mfma_f32_16x16x32_bf16(ah, bh, acc[mtl], 0, 0, 0);
                acc[mtl] = __builtin_amdgcn_mfma_f32_16x16x32_bf16(ah, bl, acc[mtl], 0, 0, 0);
                acc[mtl] = __builtin_amdgcn_mfma_f32_16x16x32_bf16(al, bh, acc[mtl], 0, 0, 0);
            }
        }
    }
    #pragma unroll
    for (int mtl = 0; mtl < 2; ++mtl)
        #pragma unroll
        for (int reg = 0; reg < 4; ++reg) {
            int m  = m0 + mtl*16 + q*4 + reg;
            G[(size_t)m * NP + np0 + wv*16 + l16] = acc[mtl][reg];
        }
}

// ---- pass 2b + routing update: db -> blog, eblog=exp(blog), expsum ------
// grid (18 j-tiles of 64, 10 n), block 256. One atomicAdd per block.
// No max-subtraction needed: |blog| <= ~2 here, exp is safe; softmax value
// is mathematically identical (shift-invariance).
__global__ void k_wg_db(const float* __restrict__ wg, const float* __restrict__ G,
                        float* __restrict__ blog, float* __restrict__ eblog,
                        float* __restrict__ expsum, int t0) {
    const int j0 = blockIdx.x * 64, n = blockIdx.y;
    const int tid = threadIdx.x;
    const int jl = tid & 63, up = tid >> 6;
    const int j = j0 + jl;

    const float4* wp = reinterpret_cast<const float4*>(
        wg + (size_t)j * WROW + n * 128 + up * 32);
    float acc = 0.f;
    #pragma unroll
    for (int q4 = 0; q4 < 4; ++q4) {
        int u = up*4 + q4;
        const float* gp = G + (size_t)(n*16 + u) * NP + j;
        float4 w0 = wp[q4*2], w1 = wp[q4*2 + 1];
        acc = fmaf(w0.x, gp[0*JC], acc);
        acc = fmaf(w0.y, gp[1*JC], acc);
        acc = fmaf(w0.z, gp[2*JC], acc);
        acc = fmaf(w0.w, gp[3*JC], acc);
        acc = fmaf(w1.x, gp[4*JC], acc);
        acc = fmaf(w1.y, gp[5*JC], acc);
        acc = fmaf(w1.z, gp[6*JC], acc);
        acc = fmaf(w1.w, gp[7*JC], acc);
    }
    __shared__ float red[4][64];
    red[up][jl] = acc;
    __syncthreads();
    if (tid < 64) {   // exactly one wave
        int jj = j0 + tid;
        float d = (red[0][tid] + red[1][tid] + red[2][tid] + red[3][tid])
                  * (1.f / (float)B);
        float nb = t0 ? d : (blog[jj*NN + n] + d);
        blog[jj*NN + n] = nb;
        float e = __expf(nb);
        eblog[jj*NN + n] = e;
        float s = e;
        s += __shfl_xor(s, 1);  s += __shfl_xor(s, 2);
        s += __shfl_xor(s, 4);  s += __shfl_xor(s, 8);
        s += __shfl_xor(s, 16); s += __shfl_xor(s, 32);
        if (tid == 0) atomicAdd(&expsum[n], s);
    }
}

extern "C" void kernel_launch(void* const* d_in, const int* in_sizes, int n_in,
                              void* d_out, int out_size, void* d_ws, size_t ws_size,
                              hipStream_t stream) {
    const float* x = (const float*)d_in[0];
    const float* w = (const float*)d_in[1];
    float* out = (float*)d_out;

    float* ws     = (float*)d_ws;
    float* blog   = ws;                           // 11520
    float* eblog  = blog + JN;                    // 11520
    float* expsum = eblog + JN;                   // 16 (padded)
    float* v      = expsum + 16;                  // 40960
    float* s_part = v + (size_t)B*NU;             // 72*40960 = 2,949,120
    float* G      = s_part + (size_t)KB * 40960;  // 1,474,560
    // total ≈ 17.9 MB

    for (int t = 0; t < 3; ++t) {
        k_gemm1<<<dim3(KB, 8), 256, 0, stream>>>(
            x, w, (t == 0) ? nullptr : eblog, expsum, s_part);
        k_reduce_s<<<B, 320, 0, stream>>>(s_part, (t == 2) ? out : v);
        if (t < 2) {
            k_vxg<<<dim3(144, 5), 256, 0, stream>>>(v, x, G, expsum);
            k_wg_db<<<dim3(18, 10), 256, 0, stream>>>(w, G, blog, eblog, expsum,
                                                      (t == 0) ? 1 : 0);
        }
    }
}

// Round 2
// 144.110 us; speedup vs baseline: 1.0215x; 1.0215x over previous
//
#include <hip/hip_runtime.h>
#include <stdint.h>

#define B   256
#define IU  8      // in_units (i)
#define JC  1152   // in_channels (j)
#define NN  10     // num_units (n)
#define UU  16     // unit_size (u)
#define NU  160    // NN*UU
#define JN  11520  // JC*NN
#define WROW 1280  // NN*UU*IU, floats per j in W
#define NP  9216   // IU*JC, x row length
#define KB  36     // k-split count (32 j per slice, 4 chunks of 8)

typedef short bf16x8 __attribute__((ext_vector_type(8)));
typedef float f32x4  __attribute__((ext_vector_type(4)));

__device__ __forceinline__ short f2bf(float f) {
    union { float f; uint32_t u; } cv; cv.f = f;
    uint32_t u = cv.u;
    uint32_t r = u + 0x7fffu + ((u >> 16) & 1u);
    return (short)(r >> 16);
}
__device__ __forceinline__ float bf2f(short h) {
    union { uint32_t u; float f; } cv; cv.u = ((uint32_t)(unsigned short)h) << 16;
    return cv.f;
}
__device__ __forceinline__ uint32_t bfbits(float f) {
    union { float f; uint32_t u; } cv; cv.f = f;
    return (cv.u + 0x7fffu + ((cv.u >> 16) & 1u)) >> 16;
}
__device__ __forceinline__ uint32_t pk2(float a, float b) {
    return bfbits(a) | (bfbits(b) << 16);
}
__device__ __forceinline__ void gload16(const void* g, void* l) {
    __builtin_amdgcn_global_load_lds(
        (const __attribute__((address_space(1))) void*)g,
        (__attribute__((address_space(3))) void*)l, 16, 0, 0);
}

// ---------------- prep: W->bf16 (linear), x->bf16 transposed [j][b*8+i] --
// grid 1296: blocks 0..575 transpose x (64x64 tiles), 576..1295 convert W.
__global__ void __launch_bounds__(256)
k_prep(const float* __restrict__ xg, const float* __restrict__ wg,
       short* __restrict__ wbf, short* __restrict__ xbf) {
    const int bid = blockIdx.x, tid = threadIdx.x;
    if (bid < 576) {
        // x viewed as [2048 r][1152 j], r = b*8+i; out xbf[j][r]
        const int jt = bid % 18, rt = bid / 18;
        const int j0 = jt * 64, r0 = rt * 64;
        __shared__ short T[64][72];
        #pragma unroll
        for (int p = 0; p < 4; ++p) {
            int idx = tid + 256 * p;        // 0..1023
            int row = idx >> 4;             // 0..63
            int c4  = (idx & 15) * 4;       // 0..60
            float4 xv = *reinterpret_cast<const float4*>(
                &xg[(size_t)(r0 + row) * JC + j0 + c4]);
            T[c4+0][row] = f2bf(xv.x);
            T[c4+1][row] = f2bf(xv.y);
            T[c4+2][row] = f2bf(xv.z);
            T[c4+3][row] = f2bf(xv.w);
        }
        __syncthreads();
        #pragma unroll
        for (int p = 0; p < 2; ++p) {
            int idx = tid + 256 * p;        // 0..511
            int jl = idx >> 3;              // 0..63
            int r8 = (idx & 7) * 8;         // 0..56
            uint4 d = *reinterpret_cast<const uint4*>(&T[jl][r8]);
            *reinterpret_cast<uint4*>(&xbf[(size_t)(j0 + jl) * 2048 + r0 + r8]) = d;
        }
    } else {
        const int b2 = bid - 576;           // 0..719, 2048 floats each
        size_t base = (size_t)b2 * 2048 + (size_t)tid * 8;
        float4 f0 = *reinterpret_cast<const float4*>(&wg[base]);
        float4 f1 = *reinterpret_cast<const float4*>(&wg[base + 4]);
        uint4 d;
        d.x = pk2(f0.x, f0.y); d.y = pk2(f0.z, f0.w);
        d.z = pk2(f1.x, f1.y); d.w = pk2(f1.z, f1.w);
        *reinterpret_cast<uint4*>(&wbf[base]) = d;
    }
}

// ---------------- pass 1 MFMA GEMM: s_raw = x * (e*W)^T (unnormalized) ---
// grid (KB=36 k-splits of 32 j, 8 m-tiles of 32 b) = 288 blocks; 4 waves.
// Staging is pure global_load_lds DMA from prepped bf16 operands.
// Softmax normalization (1/Z_n, or 1/JC at t=0) is applied in k_reduce_s.
__global__ void __launch_bounds__(256, 2)
k_gemm1(const short* __restrict__ xbf, const short* __restrict__ wbf,
        float* __restrict__ s_part) {
    const int kb = blockIdx.x, mt = blockIdx.y;
    const int tid = threadIdx.x;
    const int wv = tid >> 6, lane = tid & 63;
    const int q = lane >> 4, l16 = lane & 15;
    const int b0 = mt * 32;
    const int jb0 = kb * 32;
    const int mfrag = wv >> 1;          // 0..1
    const int ntb = (wv & 1) * 5;       // 0 or 5

    __shared__ __align__(16) short As[8 * 32 * 8];   // 4 KB  [jj][bl][ii]
    __shared__ __align__(16) short Bs[8 * 160 * 8];  // 20 KB [jj][nu][ii]

    f32x4 acc[5];
    #pragma unroll
    for (int nt = 0; nt < 5; ++nt) acc[nt] = (f32x4){0.f, 0.f, 0.f, 0.f};

    for (int jc = 0; jc < 4; ++jc) {
        const int j0 = jb0 + jc * 8;
        __syncthreads();
        // As: xbf[j0+jj][ (b0+bl)*8 .. +8 ] -> As[jj][bl][ii], 1 DMA/thread
        gload16(xbf + ((size_t)(j0 + (tid >> 5)) * 2048 + (size_t)(b0 + (tid & 31)) * 8),
                &As[tid * 8]);
        // Bs: wbf rows are contiguous: src = wbf + j0*1280 + ridx*8
        const short* wsrc = wbf + (size_t)j0 * WROW;
        #pragma unroll
        for (int p = 0; p < 5; ++p) {
            int ridx = tid + 256 * p;   // 0..1279 = jj*160+nu
            gload16(wsrc + (size_t)ridx * 8, &Bs[ridx * 8]);
        }
        __syncthreads();
        #pragma unroll
        for (int s = 0; s < 2; ++s) {
            int jj = s * 4 + q;
            bf16x8 av = *reinterpret_cast<const bf16x8*>(
                &As[(jj * 32 + mfrag * 16 + l16) << 3]);
            #pragma unroll
            for (int nt = 0; nt < 5; ++nt) {
                bf16x8 bv = *reinterpret_cast<const bf16x8*>(
                    &Bs[(jj * 160 + (ntb + nt) * 16 + l16) << 3]);
                acc[nt] = __builtin_amdgcn_mfma_f32_16x16x32_bf16(av, bv, acc[nt], 0, 0, 0);
            }
        }
    }
    float* dst = s_part + (size_t)(kb * 8 + mt) * 5120;
    #pragma unroll
    for (int nt = 0; nt < 5; ++nt)
        #pragma unroll
        for (int reg = 0; reg < 4; ++reg)
            dst[(mfrag * 16 + q * 4 + reg) * 160 + (ntb + nt) * 16 + l16] = acc[nt][reg];
}

// ---------------- fused reduce (36 slices) + normalize + squash ----------
__global__ void __launch_bounds__(320, 2)
k_reduce_s(const float* __restrict__ s_part, float* __restrict__ vdst,
           const float* __restrict__ expsum, int t0) {
    const int b = blockIdx.x, tid = threadIdx.x;
    const int t = tid % 160, kq = tid / 160;
    const int mt = b >> 5, bl = b & 31;
    const size_t off = (size_t)mt * 5120 + bl * 160 + t;

    __shared__ float invn[NN];
    if (tid < NN) invn[tid] = t0 ? (1.f / (float)JC) : 1.f / expsum[tid];

    float s = 0.f;
    for (int r = 0; r < 18; ++r)
        s += s_part[(size_t)(kq * 18 + r) * 40960 + off];

    __shared__ float red[2][160];
    __shared__ float sv[NU];
    __shared__ float fb[UU];
    red[kq][t] = s;
    __syncthreads();
    if (tid < NU) sv[tid] = (red[0][tid] + red[1][tid]) * invn[tid >> 4];
    __syncthreads();
    if (tid < UU) {
        float m = 0.f;
        #pragma unroll
        for (int n = 0; n < NN; ++n) { float z = sv[n*16 + tid]; m = fmaf(z, z, m); }
        fb[tid] = sqrtf(m) / (1.f + m);
    }
    __syncthreads();
    if (tid < NU)
        vdst[(size_t)b * NU + tid] = sv[tid] * fb[tid & 15];
}

// ---------------- pass 2a: G[nu][n'] = sum_b v[b][nu] * x[b][n'] ---------
// Block (0,0) also zeroes expsum for the following k_wg_db (stream-ordered).
__global__ void __launch_bounds__(256, 2)
k_vxg(const float* __restrict__ vg, const float* __restrict__ xg,
      float* __restrict__ G, float* __restrict__ expsum) {
    const int np0 = blockIdx.x * 64, m0 = blockIdx.y * 32;
    const int tid = threadIdx.x;
    const int wv = tid >> 6, lane = tid & 63;
    const int q = lane >> 4, l16 = lane & 15;

    if (blockIdx.x == 0 && blockIdx.y == 0 && tid < NN) expsum[tid] = 0.f;

    __shared__ __align__(16) short Ash[8 * 32 * 8];
    __shared__ __align__(16) short Asl[8 * 32 * 8];
    __shared__ __align__(16) short Bsh[8 * 64 * 8];
    __shared__ __align__(16) short Bsl[8 * 64 * 8];

    f32x4 acc[2];
    acc[0] = (f32x4){0.f,0.f,0.f,0.f};
    acc[1] = (f32x4){0.f,0.f,0.f,0.f};

    for (int ks = 0; ks < 4; ++ks) {
        const int b0 = ks * 64;
        __syncthreads();
        #pragma unroll
        for (int p = 0; p < 8; ++p) {
            int idx = tid + 256 * p;
            int bb = idx >> 5, ml = idx & 31;
            float vv = vg[(size_t)(b0 + bb) * NU + m0 + ml];
            short hi = f2bf(vv);
            short lo = f2bf(vv - bf2f(hi));
            int a = ((bb >> 3) * 32 + ml) * 8 + (bb & 7);
            Ash[a] = hi; Asl[a] = lo;
        }
        #pragma unroll
        for (int p = 0; p < 16; ++p) {
            int idx = tid + 256 * p;
            int bb = idx >> 6, nl = idx & 63;
            float xv = xg[(size_t)(b0 + bb) * NP + np0 + nl];
            short hi = f2bf(xv);
            short lo = f2bf(xv - bf2f(hi));
            int a = ((bb >> 3) * 64 + nl) * 8 + (bb & 7);
            Bsh[a] = hi; Bsl[a] = lo;
        }
        __syncthreads();
        #pragma unroll
        for (int s = 0; s < 2; ++s) {
            int kc = s*4 + q;
            bf16x8 bh = *reinterpret_cast<const bf16x8*>(&Bsh[((kc*64 + wv*16 + l16) << 3)]);
            bf16x8 bl = *reinterpret_cast<const bf16x8*>(&Bsl[((kc*64 + wv*16 + l16) << 3)]);
            #pragma unroll
            for (int mtl = 0; mtl < 2; ++mtl) {
                bf16x8 ah = *reinterpret_cast<const bf16x8*>(&Ash[((kc*32 + mtl*16 + l16) << 3)]);
                bf16x8 al = *reinterpret_cast<const bf16x8*>(&Asl[((kc*32 + mtl*16 + l16) << 3)]);
                acc[mtl] = __builtin_amdgcn_mfma_f32_16x16x32_bf16(ah, bh, acc[mtl], 0, 0, 0);
                acc[mtl] = __builtin_amdgcn_mfma_f32_16x16x32_bf16(ah, bl, acc[mtl], 0, 0, 0);
                acc[mtl] = __builtin_amdgcn_mfma_f32_16x16x32_bf16(al, bh, acc[mtl], 0, 0, 0);
            }
        }
    }
    #pragma unroll
    for (int mtl = 0; mtl < 2; ++mtl)
        #pragma unroll
        for (int reg = 0; reg < 4; ++reg) {
            int m  = m0 + mtl*16 + q*4 + reg;
            G[(size_t)m * NP + np0 + wv*16 + l16] = acc[mtl][reg];
        }
}

// ---- pass 2b + routing update + bf16 operand write -----------------------
// d[j,n] -> blog; e = exp(blog); expsum[n] += e; wbf[j, n-block] = bf16(e*W).
// grid (18 j-tiles of 64, 10 n), block 256.
__global__ void k_wg_db(const float* __restrict__ wg, const float* __restrict__ G,
                        float* __restrict__ blog, short* __restrict__ wbf,
                        float* __restrict__ expsum, int t0) {
    const int j0 = blockIdx.x * 64, n = blockIdx.y;
    const int tid = threadIdx.x;
    const int jl = tid & 63, up = tid >> 6;
    const int j = j0 + jl;

    const float4* wp = reinterpret_cast<const float4*>(
        wg + (size_t)j * WROW + n * 128 + up * 32);
    float4 w[8];
    #pragma unroll
    for (int k = 0; k < 8; ++k) w[k] = wp[k];

    float acc = 0.f;
    #pragma unroll
    for (int q4 = 0; q4 < 4; ++q4) {
        int u = up*4 + q4;
        const float* gp = G + (size_t)(n*16 + u) * NP + j;
        float4 w0 = w[q4*2], w1 = w[q4*2 + 1];
        acc = fmaf(w0.x, gp[0*JC], acc);
        acc = fmaf(w0.y, gp[1*JC], acc);
        acc = fmaf(w0.z, gp[2*JC], acc);
        acc = fmaf(w0.w, gp[3*JC], acc);
        acc = fmaf(w1.x, gp[4*JC], acc);
        acc = fmaf(w1.y, gp[5*JC], acc);
        acc = fmaf(w1.z, gp[6*JC], acc);
        acc = fmaf(w1.w, gp[7*JC], acc);
    }
    __shared__ float red[4][64];
    __shared__ float esh[64];
    __shared__ __align__(16) short Wsh[64][136];
    red[up][jl] = acc;
    __syncthreads();
    if (tid < 64) {   // exactly one wave
        int jj = j0 + tid;
        float d = (red[0][tid] + red[1][tid] + red[2][tid] + red[3][tid])
                  * (1.f / (float)B);
        float nb = t0 ? d : (blog[jj*NN + n] + d);
        blog[jj*NN + n] = nb;
        float e = __expf(nb);
        esh[tid] = e;
        float s = e;
        s += __shfl_xor(s, 1);  s += __shfl_xor(s, 2);
        s += __shfl_xor(s, 4);  s += __shfl_xor(s, 8);
        s += __shfl_xor(s, 16); s += __shfl_xor(s, 32);
        if (tid == 0) atomicAdd(&expsum[n], s);
    }
    __syncthreads();
    const float e = esh[jl];
    #pragma unroll
    for (int q4 = 0; q4 < 4; ++q4) {
        float4 a = w[q4*2], bq = w[q4*2 + 1];
        uint4 d;
        d.x = pk2(a.x * e, a.y * e);
        d.y = pk2(a.z * e, a.w * e);
        d.z = pk2(bq.x * e, bq.y * e);
        d.w = pk2(bq.z * e, bq.w * e);
        *reinterpret_cast<uint4*>(&Wsh[jl][up*32 + q4*8]) = d;
    }
    __syncthreads();
    #pragma unroll
    for (int p = 0; p < 4; ++p) {
        int idx = tid + 256 * p;        // 0..1023
        int jj = idx >> 4, seg = idx & 15;
        uint4 d = *reinterpret_cast<const uint4*>(&Wsh[jj][seg * 8]);
        *reinterpret_cast<uint4*>(&wbf[(size_t)(j0 + jj) * WROW + n*128 + seg*8]) = d;
    }
}

extern "C" void kernel_launch(void* const* d_in, const int* in_sizes, int n_in,
                              void* d_out, int out_size, void* d_ws, size_t ws_size,
                              hipStream_t stream) {
    const float* x = (const float*)d_in[0];
    const float* w = (const float*)d_in[1];
    float* out = (float*)d_out;

    float* ws     = (float*)d_ws;
    float* blog   = ws;                           // 11520 f
    float* expsum = blog + JN;                    // 16 f
    float* v      = expsum + 16;                  // 40960 f
    short* wbf    = (short*)(v + (size_t)B * NU); // 1,474,560 bf16 (2.95 MB)
    short* xbf    = wbf + (size_t)JC * WROW;      // 2,359,296 bf16 (4.72 MB)
    float* s_part = (float*)(xbf + (size_t)JC * 2048); // 36*40960 f (5.9 MB)
    float* G      = s_part;                       // alias: disjoint lifetime
    // total ≈ 13.8 MB

    k_prep<<<1296, 256, 0, stream>>>(x, w, wbf, xbf);
    for (int t = 0; t < 3; ++t) {
        k_gemm1<<<dim3(KB, 8), 256, 0, stream>>>(xbf, wbf, s_part);
        k_reduce_s<<<B, 320, 0, stream>>>(s_part, (t == 2) ? out : v, expsum,
                                          (t == 0) ? 1 : 0);
        if (t < 2) {
            k_vxg<<<dim3(144, 5), 256, 0, stream>>>(v, x, G, expsum);
            k_wg_db<<<dim3(18, 10), 256, 0, stream>>>(w, G, blog, wbf, expsum,
                                                      (t == 0) ? 1 : 0);
        }
    }
}